// Round 7
// baseline (126.113 us; speedup 1.0000x reference)
//
#include <hip/hip_runtime.h>
#include <math.h>

#define Bq 4
#define Nq 128
#define Cq 256
#define HFq 23
#define WFq 30
#define PHq 7
#define PWq 7
#define HIDq 256
#define OUTq 5
#define Fq (Cq*PHq*PWq)      // 12544
#define Mq (Bq*Nq)           // 512
#define HWq (HFq*WFq)        // 690
#define SCALEq (1.0f/32.0f)
#define NEGq (-1e30f)
#define KHq 5                // HF//PH + 2
#define KWq 6                // WF//PW + 2
#define SPLITK 14
#define KCH (Fq/SPLITK)      // 896
#define BKq 64
#define KSTEPS (KCH/BKq)     // 14

typedef float f32x4 __attribute__((ext_vector_type(4)));
typedef __bf16 bf16x8 __attribute__((ext_vector_type(8)));
typedef unsigned short u16x8 __attribute__((ext_vector_type(8)));

__device__ __forceinline__ unsigned short f2b(float f) {
    unsigned int u = __float_as_uint(f);
    unsigned int r = (u + 0x7FFFu + ((u >> 16) & 1u)) >> 16;
    return (unsigned short)r;
}

// K1: fused prep. blockIdx.x ranges:
//   [0,704)   : transpose features (B,C,HF,WF) f32 -> (B, HF*WF, C) bf16
//   [704,960) : W1 f32 (HID, c*49+cell) -> bf16 permuted (HID, cell*256+c)
//   [960,968) : zero h (atomicAdd target) + m-tile completion counters
__global__ __launch_bounds__(256) void k_prep(const float* __restrict__ feat,
                                              unsigned short* __restrict__ ft,
                                              const float* __restrict__ W1,
                                              unsigned short* __restrict__ w1p,
                                              float* __restrict__ h,
                                              int* __restrict__ cnt) {
    __shared__ __align__(16) unsigned short smem[Fq];   // 25088 B overlay
    int bid = blockIdx.x;
    int tid = threadIdx.x;
    if (bid < 704) {
        // --- transpose tile, f32 -> bf16 ---
        float (*t)[33] = (float (*)[33])smem;           // 32*33*4 = 4224 B
        int bb  = bid / 176;
        int rem = bid % 176;
        int x0 = (rem % 22) * 32;      // HW dim
        int c0 = (rem / 22) * 32;      // C dim
        int tx = tid & 31, ty = tid >> 5;
        const float* src = feat + (size_t)bb * Cq * HWq;
        unsigned short* dst = ft + (size_t)bb * HWq * Cq;
#pragma unroll
        for (int i = 0; i < 4; ++i) {
            int c = c0 + ty + i * 8;
            int x = x0 + tx;
            if (x < HWq) t[ty + i * 8][tx] = src[(size_t)c * HWq + x];  // t[c_loc][x_loc]
        }
        __syncthreads();
        int u = tid & 15, xl = tid >> 4;
#pragma unroll
        for (int i = 0; i < 2; ++i) {
            int xloc = xl + i * 16;
            int x = x0 + xloc;
            if (x < HWq) {
                ushort2 o;
                o.x = f2b(t[u * 2][xloc]);
                o.y = f2b(t[u * 2 + 1][xloc]);
                *(ushort2*)(dst + (size_t)x * Cq + c0 + u * 2) = o;
            }
        }
    } else if (bid < 960) {
        // --- W1 permute + bf16 convert ---
        int j = bid - 704;
        const float4* src = (const float4*)(W1 + (size_t)j * Fq);
        for (int i = tid; i < Fq / 4; i += 256) {
            float4 v = src[i];
            ushort4 o;
            o.x = f2b(v.x); o.y = f2b(v.y); o.z = f2b(v.z); o.w = f2b(v.w);
            ((ushort4*)smem)[i] = o;
        }
        __syncthreads();
        uint4* dst = (uint4*)(w1p + (size_t)j * Fq);
        for (int i = tid; i < Fq / 8; i += 256) {
            int base = i * 8;
            int cell = base >> 8;       // 8 consecutive c share one cell
            int c0v = base & 255;
            unsigned short tmp[8];
#pragma unroll
            for (int u2 = 0; u2 < 8; ++u2) tmp[u2] = smem[(c0v + u2) * 49 + cell];
            dst[i] = *(const uint4*)tmp;
        }
    } else {
        // --- zero h: 512 KB, 8 blocks x 256 threads x 16 float4 ---
        f32x4* h4 = (f32x4*)h;
        int base = (bid - 960) * 4096;
        f32x4 z = {0.f, 0.f, 0.f, 0.f};
#pragma unroll
        for (int u2 = 0; u2 < 16; ++u2) h4[base + u2 * 256 + tid] = z;
        if (bid == 960 && tid < Mq / 64) cnt[tid] = 0;
    }
}

// K2: ROI max pool over bf16 ft. ONE CELL PER WAVE: grid (Mq,13), wave g =
// blockIdx.y*4+wave handles cell g (g<49). ~25k waves -> max latency hiding.
// Lane split: cl = lane&31 -> 8 channels; half = lane>>5 -> w-positions.
// Combine via shfl_xor(32).
__global__ __launch_bounds__(256) void k_pool(const unsigned short* __restrict__ ft,
                                              const float* __restrict__ props,
                                              unsigned short* __restrict__ pooled) {
    int wave = threadIdx.x >> 6;
    int lane = threadIdx.x & 63;
    int half = lane >> 5;
    int cl = lane & 31;
    int cell = blockIdx.y * 4 + wave;   // 0..51
    if (cell >= PHq * PWq) return;
    int m = blockIdx.x;              // proposal
    int b = m >> 7;
    const float* pr = props + (size_t)m * 5;
    float b0 = pr[0] * SCALEq, b1v = pr[1] * SCALEq;
    float b2v = pr[2] * SCALEq, b3v = pr[3] * SCALEq;
    int x1 = min(max((int)floorf(b0), 0), WFq - 1);
    int y1 = min(max((int)floorf(b1v), 0), HFq - 1);
    int rw = min(max((int)ceilf(b2v) - x1, 1), WFq);
    int rh = min(max((int)ceilf(b3v) - y1, 1), HFq);
    const unsigned short* ftb = ft + (size_t)b * HWq * Cq + cl * 8;
    unsigned short* pm = pooled + (size_t)m * Fq + cl * 8;

    int ph = cell / 7;
    int pw = cell - ph * 7;
    int hs = y1 + (ph * rh) / PHq;
    int he = min(y1 + ((ph + 1) * rh + PHq - 1) / PHq, HFq);
    int ws = x1 + (pw * rw) / PWq;
    int we = min(x1 + ((pw + 1) * rw + PWq - 1) / PWq, WFq);
    float acc[8];
#pragma unroll
    for (int u = 0; u < 8; ++u) acc[u] = NEGq;
#pragma unroll
    for (int kh = 0; kh < KHq; ++kh) {
        if (hs + kh < he) {                      // wave-uniform
            const unsigned short* rowp = ftb + (size_t)((hs + kh) * WFq) * Cq;
#pragma unroll
            for (int kw2 = 0; kw2 < 3; ++kw2) {
                int w = ws + kw2 * 2 + half;
                if (w < we) {                    // half-wave divergent only
                    u16x8 v = *(const u16x8*)(rowp + (size_t)w * Cq);
#pragma unroll
                    for (int u = 0; u < 8; ++u)
                        acc[u] = fmaxf(acc[u], __uint_as_float((unsigned)v[u] << 16));
                }
            }
        }
    }
#pragma unroll
    for (int u = 0; u < 8; ++u) acc[u] = fmaxf(acc[u], __shfl_xor(acc[u], 32));
    if (half == 0) {
        u16x8 o;
#pragma unroll
        for (int u = 0; u < 8; ++u) o[u] = f2b(acc[u]);
        *(u16x8*)(pm + (size_t)cell * Cq) = o;
    }
}

// K3: GEMM1 with MFMA bf16 + FUSED TAIL. BM=64, BN=64, BK=64, double-buffered
// LDS, XOR-swizzled 16B chunks -> conflict-free ds_read_b128. Split-K into h
// via atomicAdd. Each m-tile is touched by 4*SPLITK = 56 blocks; the LAST
// arrival (device-scope ACQ_REL counter) runs GEMM2 + epilogue for its 64 rows.
__global__ __launch_bounds__(256) void k_gemm1(const unsigned short* __restrict__ pooled,
                                               const unsigned short* __restrict__ w1p,
                                               float* __restrict__ h,
                                               int* __restrict__ cnt,
                                               const float* __restrict__ b1,
                                               const float* __restrict__ W2,
                                               const float* __restrict__ b2,
                                               const float* __restrict__ props,
                                               float* __restrict__ out) {
    __shared__ __align__(16) unsigned short As[2][64 * BKq];  // 2 x 8 KB
    __shared__ __align__(16) unsigned short Bs[2][64 * BKq];  // 2 x 8 KB
    __shared__ int fin;
    int m0 = blockIdx.x * 64;
    int j0 = blockIdx.y * 64;
    int kz = blockIdx.z;
    int tid = threadIdx.x;
    int r = tid >> 2, qq = tid & 3;
    const uint4* ap = (const uint4*)(pooled + (size_t)(m0 + r) * Fq + (size_t)kz * KCH) + qq;
    const uint4* bp = (const uint4*)(w1p + (size_t)(j0 + r) * Fq + (size_t)kz * KCH) + qq;
    int lane = tid & 63, wv = tid >> 6;
    int q = lane >> 4, mr = lane & 15;
    f32x4 acc0 = {0.f, 0.f, 0.f, 0.f};
    f32x4 acc1 = {0.f, 0.f, 0.f, 0.f};
    f32x4 acc2 = {0.f, 0.f, 0.f, 0.f};
    f32x4 acc3 = {0.f, 0.f, 0.f, 0.f};
    // staging (uint4 units): row r, chunks qq and qq^4, swizzled by r&7
    int st1 = r * 8 + ((qq) ^ (r & 7));
    int st2 = r * 8 + ((qq ^ 4) ^ (r & 7));
    // fragment read offsets (uint4 units): row*8 + ((kk*4+q) ^ (mr&7))
    int sA = (wv * 16 + mr) * 8;
    int c0k0 = (q) ^ (mr & 7);        // kk=0 chunk
    int c0k1 = (q ^ 4) ^ (mr & 7);    // kk=1 chunk

    uint4 a0v = ap[0], a1v = ap[4];
    uint4 b0v = bp[0], b1v = bp[4];
    {   // write step 0 into buf 0
        uint4* aw = (uint4*)As[0];
        uint4* bw = (uint4*)Bs[0];
        aw[st1] = a0v; aw[st2] = a1v;
        bw[st1] = b0v; bw[st2] = b1v;
    }
    a0v = ap[8];  a1v = ap[12];
    b0v = bp[8];  b1v = bp[12];
    for (int s = 0; s < KSTEPS; ++s) {
        __syncthreads();
        int cur = s & 1;
        if (s + 1 < KSTEPS) {
            uint4* aw = (uint4*)As[cur ^ 1];
            uint4* bw = (uint4*)Bs[cur ^ 1];
            aw[st1] = a0v; aw[st2] = a1v;
            bw[st1] = b0v; bw[st2] = b1v;
            if (s + 2 < KSTEPS) {
                a0v = ap[(s + 2) * 8];     a1v = ap[(s + 2) * 8 + 4];
                b0v = bp[(s + 2) * 8];     b1v = bp[(s + 2) * 8 + 4];
            }
        }
        const bf16x8* Ab = (const bf16x8*)As[cur];
        const bf16x8* Bb = (const bf16x8*)Bs[cur];
        bf16x8 a0 = Ab[sA + c0k0];
        bf16x8 a1 = Ab[sA + c0k1];
        acc0 = __builtin_amdgcn_mfma_f32_16x16x32_bf16(a0, Bb[(0  + mr) * 8 + c0k0], acc0, 0, 0, 0);
        acc1 = __builtin_amdgcn_mfma_f32_16x16x32_bf16(a0, Bb[(16 + mr) * 8 + c0k0], acc1, 0, 0, 0);
        acc2 = __builtin_amdgcn_mfma_f32_16x16x32_bf16(a0, Bb[(32 + mr) * 8 + c0k0], acc2, 0, 0, 0);
        acc3 = __builtin_amdgcn_mfma_f32_16x16x32_bf16(a0, Bb[(48 + mr) * 8 + c0k0], acc3, 0, 0, 0);
        acc0 = __builtin_amdgcn_mfma_f32_16x16x32_bf16(a1, Bb[(0  + mr) * 8 + c0k1], acc0, 0, 0, 0);
        acc1 = __builtin_amdgcn_mfma_f32_16x16x32_bf16(a1, Bb[(16 + mr) * 8 + c0k1], acc1, 0, 0, 0);
        acc2 = __builtin_amdgcn_mfma_f32_16x16x32_bf16(a1, Bb[(32 + mr) * 8 + c0k1], acc2, 0, 0, 0);
        acc3 = __builtin_amdgcn_mfma_f32_16x16x32_bf16(a1, Bb[(48 + mr) * 8 + c0k1], acc3, 0, 0, 0);
    }
    int mb = m0 + wv * 16 + q * 4;
    int jj = j0 + mr;
#pragma unroll
    for (int r2 = 0; r2 < 4; ++r2) {
        float* row = h + (size_t)(mb + r2) * HIDq + jj;
        atomicAdd(row + 0,  acc0[r2]);
        atomicAdd(row + 16, acc1[r2]);
        atomicAdd(row + 32, acc2[r2]);
        atomicAdd(row + 48, acc3[r2]);
    }
    // --- last-arrival tail: GEMM2 (64 x 5 x 256) + epilogue for rows m0..m0+63
    __syncthreads();   // drains vmcnt -> this block's h atomics complete
    if (tid == 0) {
        int old = __hip_atomic_fetch_add(&cnt[blockIdx.x], 1,
                                         __ATOMIC_ACQ_REL, __HIP_MEMORY_SCOPE_AGENT);
        fin = (old == 4 * SPLITK - 1);
    }
    __syncthreads();
    if (!fin) return;
    // wave wv handles rows m0 + wv*16 .. +15; lane owns 4 channels j = lane*4+u
    int j4 = lane * 4;
    float b14[4], w2r[OUTq][4];
#pragma unroll
    for (int u = 0; u < 4; ++u) b14[u] = b1[j4 + u];
#pragma unroll
    for (int o = 0; o < OUTq; ++o)
#pragma unroll
        for (int u = 0; u < 4; ++u) w2r[o][u] = W2[(size_t)o * HIDq + j4 + u];
#pragma unroll
    for (int rr = 0; rr < 16; ++rr) {
        int m = m0 + wv * 16 + rr;
        float hv[4];
#pragma unroll
        for (int u = 0; u < 4; ++u) {
            float hl = __hip_atomic_load(&h[(size_t)m * HIDq + j4 + u],
                                         __ATOMIC_RELAXED, __HIP_MEMORY_SCOPE_AGENT);
            hv[u] = fmaxf(hl + b14[u], 0.f);
        }
        float s[OUTq];
#pragma unroll
        for (int o = 0; o < OUTq; ++o) {
            float v = hv[0] * w2r[o][0] + hv[1] * w2r[o][1]
                    + hv[2] * w2r[o][2] + hv[3] * w2r[o][3];
            v += __shfl_xor(v, 1);
            v += __shfl_xor(v, 2);
            v += __shfl_xor(v, 4);
            v += __shfl_xor(v, 8);
            v += __shfl_xor(v, 16);
            v += __shfl_xor(v, 32);
            s[o] = v;
        }
        if (lane < OUTq) {
            float so = lane == 0 ? s[0] : lane == 1 ? s[1] : lane == 2 ? s[2]
                     : lane == 3 ? s[3] : s[4];
            so += b2[lane];
            float pv = props[(size_t)m * 5 + lane];
            float rres;
            if (lane < 4) rres = pv + so;
            else rres = 1.f / (1.f + expf(-(pv + so)));
            out[(size_t)m * 5 + lane] = rres;
        }
    }
}

extern "C" void kernel_launch(void* const* d_in, const int* in_sizes, int n_in,
                              void* d_out, int out_size, void* d_ws, size_t ws_size,
                              hipStream_t stream) {
    const float* feat  = (const float*)d_in[0];   // (4,256,23,30)
    const float* props = (const float*)d_in[1];   // (4,128,5)
    const float* W1    = (const float*)d_in[2];   // (256,12544)
    const float* b1    = (const float*)d_in[3];   // (256,)
    const float* W2    = (const float*)d_in[4];   // (5,256)
    const float* b2    = (const float*)d_in[5];   // (5,)
    float* out = (float*)d_out;

    char* ws = (char*)d_ws;
    unsigned short* ft     = (unsigned short*)(ws);              // 1,413,120 B (bf16)
    unsigned short* w1p    = (unsigned short*)(ws + 1413120);    // 6,422,528 B
    unsigned short* pooled = (unsigned short*)(ws + 7835648);    // 12,845,056 B
    float* h               = (float*)(ws + 20680704);            // 524,288 B
    int* cnt               = (int*)(ws + 21204992);              // 32 B -> 21,205,024 total

    k_prep<<<968, 256, 0, stream>>>(feat, ft, W1, w1p, h, cnt);
    k_pool<<<dim3(Mq, 13), 256, 0, stream>>>(ft, props, pooled);
    k_gemm1<<<dim3(Mq / 64, HIDq / 64, SPLITK), 256, 0, stream>>>(
        pooled, w1p, h, cnt, b1, W2, b2, props, out);
}

// Round 9
// 124.901 us; speedup vs baseline: 1.0097x; 1.0097x over previous
//
#include <hip/hip_runtime.h>
#include <math.h>

#define Bq 4
#define Nq 128
#define Cq 256
#define HFq 23
#define WFq 30
#define PHq 7
#define PWq 7
#define HIDq 256
#define OUTq 5
#define Fq (Cq*PHq*PWq)      // 12544
#define Mq (Bq*Nq)           // 512
#define HWq (HFq*WFq)        // 690
#define SCALEq (1.0f/32.0f)
#define NEGq (-1e30f)
#define KHq 5                // HF//PH + 2
#define KWq 6                // WF//PW + 2
#define SPLITK 14
#define KCH (Fq/SPLITK)      // 896
#define BKq 64
#define KSTEPS (KCH/BKq)     // 14

typedef float f32x4 __attribute__((ext_vector_type(4)));
typedef __bf16 bf16x8 __attribute__((ext_vector_type(8)));
typedef unsigned short u16x8 __attribute__((ext_vector_type(8)));

__device__ __forceinline__ unsigned short f2b(float f) {
    unsigned int u = __float_as_uint(f);
    unsigned int r = (u + 0x7FFFu + ((u >> 16) & 1u)) >> 16;
    return (unsigned short)r;
}

// K1: fused prep. blockIdx.x ranges:
//   [0,704)   : transpose features (B,C,HF,WF) f32 -> (B, HF*WF, C) bf16
//   [704,960) : W1 f32 (HID, c*49+cell) -> bf16 permuted (HID, cell*256+c)
//   [960,968) : zero h (atomicAdd target) + m-tile completion counters
__global__ __launch_bounds__(256) void k_prep(const float* __restrict__ feat,
                                              unsigned short* __restrict__ ft,
                                              const float* __restrict__ W1,
                                              unsigned short* __restrict__ w1p,
                                              float* __restrict__ h,
                                              int* __restrict__ cnt) {
    __shared__ __align__(16) unsigned short smem[Fq];   // 25088 B overlay
    int bid = blockIdx.x;
    int tid = threadIdx.x;
    if (bid < 704) {
        // --- transpose tile, f32 -> bf16 ---
        float (*t)[33] = (float (*)[33])smem;           // 32*33*4 = 4224 B
        int bb  = bid / 176;
        int rem = bid % 176;
        int x0 = (rem % 22) * 32;      // HW dim
        int c0 = (rem / 22) * 32;      // C dim
        int tx = tid & 31, ty = tid >> 5;
        const float* src = feat + (size_t)bb * Cq * HWq;
        unsigned short* dst = ft + (size_t)bb * HWq * Cq;
#pragma unroll
        for (int i = 0; i < 4; ++i) {
            int c = c0 + ty + i * 8;
            int x = x0 + tx;
            if (x < HWq) t[ty + i * 8][tx] = src[(size_t)c * HWq + x];  // t[c_loc][x_loc]
        }
        __syncthreads();
        int u = tid & 15, xl = tid >> 4;
#pragma unroll
        for (int i = 0; i < 2; ++i) {
            int xloc = xl + i * 16;
            int x = x0 + xloc;
            if (x < HWq) {
                ushort2 o;
                o.x = f2b(t[u * 2][xloc]);
                o.y = f2b(t[u * 2 + 1][xloc]);
                *(ushort2*)(dst + (size_t)x * Cq + c0 + u * 2) = o;
            }
        }
    } else if (bid < 960) {
        // --- W1 permute + bf16 convert ---
        int j = bid - 704;
        const float4* src = (const float4*)(W1 + (size_t)j * Fq);
        for (int i = tid; i < Fq / 4; i += 256) {
            float4 v = src[i];
            ushort4 o;
            o.x = f2b(v.x); o.y = f2b(v.y); o.z = f2b(v.z); o.w = f2b(v.w);
            ((ushort4*)smem)[i] = o;
        }
        __syncthreads();
        uint4* dst = (uint4*)(w1p + (size_t)j * Fq);
        for (int i = tid; i < Fq / 8; i += 256) {
            int base = i * 8;
            int cell = base >> 8;       // 8 consecutive c share one cell
            int c0v = base & 255;
            unsigned short tmp[8];
#pragma unroll
            for (int u2 = 0; u2 < 8; ++u2) tmp[u2] = smem[(c0v + u2) * 49 + cell];
            dst[i] = *(const uint4*)tmp;
        }
    } else {
        // --- zero h: 512 KB, 8 blocks x 256 threads x 16 float4 ---
        f32x4* h4 = (f32x4*)h;
        int base = (bid - 960) * 4096;
        f32x4 z = {0.f, 0.f, 0.f, 0.f};
#pragma unroll
        for (int u2 = 0; u2 < 16; ++u2) h4[base + u2 * 256 + tid] = z;
        if (bid == 960 && tid < Mq / 64) cnt[tid] = 0;
    }
}

// K2: ROI max pool over bf16 ft. ONE CELL PER WAVE: grid (Mq,13), wave g =
// blockIdx.y*4+wave handles cell g (g<49). ~25k waves -> max latency hiding.
__global__ __launch_bounds__(256) void k_pool(const unsigned short* __restrict__ ft,
                                              const float* __restrict__ props,
                                              unsigned short* __restrict__ pooled) {
    int wave = threadIdx.x >> 6;
    int lane = threadIdx.x & 63;
    int half = lane >> 5;
    int cl = lane & 31;
    int cell = blockIdx.y * 4 + wave;   // 0..51
    if (cell >= PHq * PWq) return;
    int m = blockIdx.x;              // proposal
    int b = m >> 7;
    const float* pr = props + (size_t)m * 5;
    float b0 = pr[0] * SCALEq, b1v = pr[1] * SCALEq;
    float b2v = pr[2] * SCALEq, b3v = pr[3] * SCALEq;
    int x1 = min(max((int)floorf(b0), 0), WFq - 1);
    int y1 = min(max((int)floorf(b1v), 0), HFq - 1);
    int rw = min(max((int)ceilf(b2v) - x1, 1), WFq);
    int rh = min(max((int)ceilf(b3v) - y1, 1), HFq);
    const unsigned short* ftb = ft + (size_t)b * HWq * Cq + cl * 8;
    unsigned short* pm = pooled + (size_t)m * Fq + cl * 8;

    int ph = cell / 7;
    int pw = cell - ph * 7;
    int hs = y1 + (ph * rh) / PHq;
    int he = min(y1 + ((ph + 1) * rh + PHq - 1) / PHq, HFq);
    int ws = x1 + (pw * rw) / PWq;
    int we = min(x1 + ((pw + 1) * rw + PWq - 1) / PWq, WFq);
    float acc[8];
#pragma unroll
    for (int u = 0; u < 8; ++u) acc[u] = NEGq;
#pragma unroll
    for (int kh = 0; kh < KHq; ++kh) {
        if (hs + kh < he) {                      // wave-uniform
            const unsigned short* rowp = ftb + (size_t)((hs + kh) * WFq) * Cq;
#pragma unroll
            for (int kw2 = 0; kw2 < 3; ++kw2) {
                int w = ws + kw2 * 2 + half;
                if (w < we) {                    // half-wave divergent only
                    u16x8 v = *(const u16x8*)(rowp + (size_t)w * Cq);
#pragma unroll
                    for (int u = 0; u < 8; ++u)
                        acc[u] = fmaxf(acc[u], __uint_as_float((unsigned)v[u] << 16));
                }
            }
        }
    }
#pragma unroll
    for (int u = 0; u < 8; ++u) acc[u] = fmaxf(acc[u], __shfl_xor(acc[u], 32));
    if (half == 0) {
        u16x8 o;
#pragma unroll
        for (int u = 0; u < 8; ++u) o[u] = f2b(acc[u]);
        *(u16x8*)(pm + (size_t)cell * Cq) = o;
    }
}

// K3: GEMM1 (MFMA bf16) + fused last-arrival tail.
// Completion counter is RELAXED agent-scope (no per-block L2 wb/inv).
// h flows through agent-scope atomics (coherent point, cache-bypassing);
// __syncthreads() drains vmcnt(0) before the counter bump. Only the 8
// finisher blocks execute one ACQUIRE fence (__builtin_amdgcn_fence).
__global__ __launch_bounds__(256) void k_gemm1(const unsigned short* __restrict__ pooled,
                                               const unsigned short* __restrict__ w1p,
                                               float* __restrict__ h,
                                               int* __restrict__ cnt,
                                               const float* __restrict__ b1,
                                               const float* __restrict__ W2,
                                               const float* __restrict__ b2,
                                               const float* __restrict__ props,
                                               float* __restrict__ out) {
    __shared__ __align__(16) unsigned short As[2][64 * BKq];  // 2 x 8 KB
    __shared__ __align__(16) unsigned short Bs[2][64 * BKq];  // 2 x 8 KB
    __shared__ int fin;
    int m0 = blockIdx.x * 64;
    int j0 = blockIdx.y * 64;
    int kz = blockIdx.z;
    int tid = threadIdx.x;
    int r = tid >> 2, qq = tid & 3;
    const uint4* ap = (const uint4*)(pooled + (size_t)(m0 + r) * Fq + (size_t)kz * KCH) + qq;
    const uint4* bp = (const uint4*)(w1p + (size_t)(j0 + r) * Fq + (size_t)kz * KCH) + qq;
    int lane = tid & 63, wv = tid >> 6;
    int q = lane >> 4, mr = lane & 15;
    f32x4 acc0 = {0.f, 0.f, 0.f, 0.f};
    f32x4 acc1 = {0.f, 0.f, 0.f, 0.f};
    f32x4 acc2 = {0.f, 0.f, 0.f, 0.f};
    f32x4 acc3 = {0.f, 0.f, 0.f, 0.f};
    int st1 = r * 8 + ((qq) ^ (r & 7));
    int st2 = r * 8 + ((qq ^ 4) ^ (r & 7));
    int sA = (wv * 16 + mr) * 8;
    int c0k0 = (q) ^ (mr & 7);        // kk=0 chunk
    int c0k1 = (q ^ 4) ^ (mr & 7);    // kk=1 chunk

    uint4 a0v = ap[0], a1v = ap[4];
    uint4 b0v = bp[0], b1v = bp[4];
    {   // write step 0 into buf 0
        uint4* aw = (uint4*)As[0];
        uint4* bw = (uint4*)Bs[0];
        aw[st1] = a0v; aw[st2] = a1v;
        bw[st1] = b0v; bw[st2] = b1v;
    }
    a0v = ap[8];  a1v = ap[12];
    b0v = bp[8];  b1v = bp[12];
    for (int s = 0; s < KSTEPS; ++s) {
        __syncthreads();
        int cur = s & 1;
        if (s + 1 < KSTEPS) {
            uint4* aw = (uint4*)As[cur ^ 1];
            uint4* bw = (uint4*)Bs[cur ^ 1];
            aw[st1] = a0v; aw[st2] = a1v;
            bw[st1] = b0v; bw[st2] = b1v;
            if (s + 2 < KSTEPS) {
                a0v = ap[(s + 2) * 8];     a1v = ap[(s + 2) * 8 + 4];
                b0v = bp[(s + 2) * 8];     b1v = bp[(s + 2) * 8 + 4];
            }
        }
        const bf16x8* Ab = (const bf16x8*)As[cur];
        const bf16x8* Bb = (const bf16x8*)Bs[cur];
        bf16x8 a0 = Ab[sA + c0k0];
        bf16x8 a1 = Ab[sA + c0k1];
        acc0 = __builtin_amdgcn_mfma_f32_16x16x32_bf16(a0, Bb[(0  + mr) * 8 + c0k0], acc0, 0, 0, 0);
        acc1 = __builtin_amdgcn_mfma_f32_16x16x32_bf16(a0, Bb[(16 + mr) * 8 + c0k0], acc1, 0, 0, 0);
        acc2 = __builtin_amdgcn_mfma_f32_16x16x32_bf16(a0, Bb[(32 + mr) * 8 + c0k0], acc2, 0, 0, 0);
        acc3 = __builtin_amdgcn_mfma_f32_16x16x32_bf16(a0, Bb[(48 + mr) * 8 + c0k0], acc3, 0, 0, 0);
        acc0 = __builtin_amdgcn_mfma_f32_16x16x32_bf16(a1, Bb[(0  + mr) * 8 + c0k1], acc0, 0, 0, 0);
        acc1 = __builtin_amdgcn_mfma_f32_16x16x32_bf16(a1, Bb[(16 + mr) * 8 + c0k1], acc1, 0, 0, 0);
        acc2 = __builtin_amdgcn_mfma_f32_16x16x32_bf16(a1, Bb[(32 + mr) * 8 + c0k1], acc2, 0, 0, 0);
        acc3 = __builtin_amdgcn_mfma_f32_16x16x32_bf16(a1, Bb[(48 + mr) * 8 + c0k1], acc3, 0, 0, 0);
    }
    int mb = m0 + wv * 16 + q * 4;
    int jj = j0 + mr;
#pragma unroll
    for (int r2 = 0; r2 < 4; ++r2) {
        float* row = h + (size_t)(mb + r2) * HIDq + jj;
        atomicAdd(row + 0,  acc0[r2]);
        atomicAdd(row + 16, acc1[r2]);
        atomicAdd(row + 32, acc2[r2]);
        atomicAdd(row + 48, acc3[r2]);
    }
    // --- last-arrival tail: GEMM2 (64 x 5 x 256) + epilogue for rows m0..m0+63
    __syncthreads();   // emits s_waitcnt vmcnt(0): this block's h atomics are
                       // complete at the coherent point before the counter bump
    if (tid == 0) {
        int old = __hip_atomic_fetch_add(&cnt[blockIdx.x], 1,
                                         __ATOMIC_RELAXED, __HIP_MEMORY_SCOPE_AGENT);
        fin = (old == 4 * SPLITK - 1);
    }
    __syncthreads();
    if (!fin) return;
    __builtin_amdgcn_fence(__ATOMIC_ACQUIRE, "agent");  // 8 finisher blocks only
    // wave wv handles rows m0 + wv*16 .. +15; lane owns 4 channels j = lane*4+u
    int j4 = lane * 4;
    float b14[4], w2r[OUTq][4];
#pragma unroll
    for (int u = 0; u < 4; ++u) b14[u] = b1[j4 + u];
#pragma unroll
    for (int o = 0; o < OUTq; ++o)
#pragma unroll
        for (int u = 0; u < 4; ++u) w2r[o][u] = W2[(size_t)o * HIDq + j4 + u];
#pragma unroll
    for (int rr = 0; rr < 16; ++rr) {
        int m = m0 + wv * 16 + rr;
        float hv[4];
#pragma unroll
        for (int u = 0; u < 4; ++u) {
            float hl = __hip_atomic_load(&h[(size_t)m * HIDq + j4 + u],
                                         __ATOMIC_RELAXED, __HIP_MEMORY_SCOPE_AGENT);
            hv[u] = fmaxf(hl + b14[u], 0.f);
        }
        float s[OUTq];
#pragma unroll
        for (int o = 0; o < OUTq; ++o) {
            float v = hv[0] * w2r[o][0] + hv[1] * w2r[o][1]
                    + hv[2] * w2r[o][2] + hv[3] * w2r[o][3];
            v += __shfl_xor(v, 1);
            v += __shfl_xor(v, 2);
            v += __shfl_xor(v, 4);
            v += __shfl_xor(v, 8);
            v += __shfl_xor(v, 16);
            v += __shfl_xor(v, 32);
            s[o] = v;
        }
        if (lane < OUTq) {
            float so = lane == 0 ? s[0] : lane == 1 ? s[1] : lane == 2 ? s[2]
                     : lane == 3 ? s[3] : s[4];
            so += b2[lane];
            float pv = props[(size_t)m * 5 + lane];
            float rres;
            if (lane < 4) rres = pv + so;
            else rres = 1.f / (1.f + expf(-(pv + so)));
            out[(size_t)m * 5 + lane] = rres;
        }
    }
}

extern "C" void kernel_launch(void* const* d_in, const int* in_sizes, int n_in,
                              void* d_out, int out_size, void* d_ws, size_t ws_size,
                              hipStream_t stream) {
    const float* feat  = (const float*)d_in[0];   // (4,256,23,30)
    const float* props = (const float*)d_in[1];   // (4,128,5)
    const float* W1    = (const float*)d_in[2];   // (256,12544)
    const float* b1    = (const float*)d_in[3];   // (256,)
    const float* W2    = (const float*)d_in[4];   // (5,256)
    const float* b2    = (const float*)d_in[5];   // (5,)
    float* out = (float*)d_out;

    char* ws = (char*)d_ws;
    unsigned short* ft     = (unsigned short*)(ws);              // 1,413,120 B (bf16)
    unsigned short* w1p    = (unsigned short*)(ws + 1413120);    // 6,422,528 B
    unsigned short* pooled = (unsigned short*)(ws + 7835648);    // 12,845,056 B
    float* h               = (float*)(ws + 20680704);            // 524,288 B
    int* cnt               = (int*)(ws + 21204992);              // 32 B -> 21,205,024 total

    k_prep<<<968, 256, 0, stream>>>(feat, ft, W1, w1p, h, cnt);
    k_pool<<<dim3(Mq, 13), 256, 0, stream>>>(ft, props, pooled);
    k_gemm1<<<dim3(Mq / 64, HIDq / 64, SPLITK), 256, 0, stream>>>(
        pooled, w1p, h, cnt, b1, W2, b2, props, out);
}

// Round 10
// 113.704 us; speedup vs baseline: 1.1091x; 1.0985x over previous
//
#include <hip/hip_runtime.h>
#include <math.h>

#define Bq 4
#define Nq 128
#define Cq 256
#define HFq 23
#define WFq 30
#define PHq 7
#define PWq 7
#define HIDq 256
#define OUTq 5
#define Fq (Cq*PHq*PWq)      // 12544
#define Mq (Bq*Nq)           // 512
#define HWq (HFq*WFq)        // 690
#define SCALEq (1.0f/32.0f)
#define NEGq (-1e30f)
#define KHq 5                // HF//PH + 2
#define KWq 6                // WF//PW + 2
#define SPLITK 28
#define KCH (Fq/SPLITK)      // 448
#define BKq 64
#define KSTEPS (KCH/BKq)     // 7

typedef float f32x4 __attribute__((ext_vector_type(4)));
typedef __bf16 bf16x8 __attribute__((ext_vector_type(8)));
typedef unsigned short u16x8 __attribute__((ext_vector_type(8)));

__device__ __forceinline__ unsigned short f2b(float f) {
    unsigned int u = __float_as_uint(f);
    unsigned int r = (u + 0x7FFFu + ((u >> 16) & 1u)) >> 16;
    return (unsigned short)r;
}

// K1: fused prep. blockIdx.x ranges:
//   [0,704)   : transpose features (B,C,HF,WF) f32 -> (B, HF*WF, C) bf16
//   [704,960) : W1 f32 (HID, c*49+cell) -> bf16 permuted (HID, cell*256+c)
//   [960,968) : zero h (atomicAdd target for split-K GEMM1)
__global__ __launch_bounds__(256) void k_prep(const float* __restrict__ feat,
                                              unsigned short* __restrict__ ft,
                                              const float* __restrict__ W1,
                                              unsigned short* __restrict__ w1p,
                                              float* __restrict__ h) {
    __shared__ __align__(16) unsigned short smem[Fq];   // 25088 B overlay
    int bid = blockIdx.x;
    int tid = threadIdx.x;
    if (bid < 704) {
        // --- transpose tile, f32 -> bf16 ---
        float (*t)[33] = (float (*)[33])smem;           // 32*33*4 = 4224 B
        int bb  = bid / 176;
        int rem = bid % 176;
        int x0 = (rem % 22) * 32;      // HW dim
        int c0 = (rem / 22) * 32;      // C dim
        int tx = tid & 31, ty = tid >> 5;
        const float* src = feat + (size_t)bb * Cq * HWq;
        unsigned short* dst = ft + (size_t)bb * HWq * Cq;
#pragma unroll
        for (int i = 0; i < 4; ++i) {
            int c = c0 + ty + i * 8;
            int x = x0 + tx;
            if (x < HWq) t[ty + i * 8][tx] = src[(size_t)c * HWq + x];  // t[c_loc][x_loc]
        }
        __syncthreads();
        int u = tid & 15, xl = tid >> 4;
#pragma unroll
        for (int i = 0; i < 2; ++i) {
            int xloc = xl + i * 16;
            int x = x0 + xloc;
            if (x < HWq) {
                ushort2 o;
                o.x = f2b(t[u * 2][xloc]);
                o.y = f2b(t[u * 2 + 1][xloc]);
                *(ushort2*)(dst + (size_t)x * Cq + c0 + u * 2) = o;
            }
        }
    } else if (bid < 960) {
        // --- W1 permute + bf16 convert ---
        int j = bid - 704;
        const float4* src = (const float4*)(W1 + (size_t)j * Fq);
        for (int i = tid; i < Fq / 4; i += 256) {
            float4 v = src[i];
            ushort4 o;
            o.x = f2b(v.x); o.y = f2b(v.y); o.z = f2b(v.z); o.w = f2b(v.w);
            ((ushort4*)smem)[i] = o;
        }
        __syncthreads();
        uint4* dst = (uint4*)(w1p + (size_t)j * Fq);
        for (int i = tid; i < Fq / 8; i += 256) {
            int base = i * 8;
            int cell = base >> 8;       // 8 consecutive c share one cell
            int c0v = base & 255;
            unsigned short tmp[8];
#pragma unroll
            for (int u2 = 0; u2 < 8; ++u2) tmp[u2] = smem[(c0v + u2) * 49 + cell];
            dst[i] = *(const uint4*)tmp;
        }
    } else {
        // --- zero h: 512 KB, 8 blocks x 256 threads x 16 float4 ---
        f32x4* h4 = (f32x4*)h;
        int base = (bid - 960) * 4096;
        f32x4 z = {0.f, 0.f, 0.f, 0.f};
#pragma unroll
        for (int u2 = 0; u2 < 16; ++u2) h4[base + u2 * 256 + tid] = z;
    }
}

// K2: ROI max pool over bf16 ft. ONE CELL PER WAVE: grid (Mq,13), wave g =
// blockIdx.y*4+wave handles cell g (g<49). ~25k waves -> max latency hiding.
__global__ __launch_bounds__(256) void k_pool(const unsigned short* __restrict__ ft,
                                              const float* __restrict__ props,
                                              unsigned short* __restrict__ pooled) {
    int wave = threadIdx.x >> 6;
    int lane = threadIdx.x & 63;
    int half = lane >> 5;
    int cl = lane & 31;
    int cell = blockIdx.y * 4 + wave;   // 0..51
    if (cell >= PHq * PWq) return;
    int m = blockIdx.x;              // proposal
    int b = m >> 7;
    const float* pr = props + (size_t)m * 5;
    float b0 = pr[0] * SCALEq, b1v = pr[1] * SCALEq;
    float b2v = pr[2] * SCALEq, b3v = pr[3] * SCALEq;
    int x1 = min(max((int)floorf(b0), 0), WFq - 1);
    int y1 = min(max((int)floorf(b1v), 0), HFq - 1);
    int rw = min(max((int)ceilf(b2v) - x1, 1), WFq);
    int rh = min(max((int)ceilf(b3v) - y1, 1), HFq);
    const unsigned short* ftb = ft + (size_t)b * HWq * Cq + cl * 8;
    unsigned short* pm = pooled + (size_t)m * Fq + cl * 8;

    int ph = cell / 7;
    int pw = cell - ph * 7;
    int hs = y1 + (ph * rh) / PHq;
    int he = min(y1 + ((ph + 1) * rh + PHq - 1) / PHq, HFq);
    int ws = x1 + (pw * rw) / PWq;
    int we = min(x1 + ((pw + 1) * rw + PWq - 1) / PWq, WFq);
    float acc[8];
#pragma unroll
    for (int u = 0; u < 8; ++u) acc[u] = NEGq;
#pragma unroll
    for (int kh = 0; kh < KHq; ++kh) {
        if (hs + kh < he) {                      // wave-uniform
            const unsigned short* rowp = ftb + (size_t)((hs + kh) * WFq) * Cq;
#pragma unroll
            for (int kw2 = 0; kw2 < 3; ++kw2) {
                int w = ws + kw2 * 2 + half;
                if (w < we) {                    // half-wave divergent only
                    u16x8 v = *(const u16x8*)(rowp + (size_t)w * Cq);
#pragma unroll
                    for (int u = 0; u < 8; ++u)
                        acc[u] = fmaxf(acc[u], __uint_as_float((unsigned)v[u] << 16));
                }
            }
        }
    }
#pragma unroll
    for (int u = 0; u < 8; ++u) acc[u] = fmaxf(acc[u], __shfl_xor(acc[u], 32));
    if (half == 0) {
        u16x8 o;
#pragma unroll
        for (int u = 0; u < 8; ++u) o[u] = f2b(acc[u]);
        *(u16x8*)(pm + (size_t)cell * Cq) = o;
    }
}

// K3: GEMM1 with MFMA bf16. BM=64, BN=64, BK=64, double-buffered LDS with
// XOR-swizzled 16B chunks (chunk' = chunk ^ (row&7)) -> conflict-free
// ds_read_b128 / 2-way (free) ds_write. 2-step register lookahead.
// SPLITK=28 (KSTEPS=7): 896 blocks = 3.5/CU for latency hiding.
// K-loop code is the verified R2 form — NO epilogue additions (fused-tail
// and BM=128 variants both regressed ~+12-15 us; codegen-fragile).
__global__ __launch_bounds__(256) void k_gemm1(const unsigned short* __restrict__ pooled,
                                               const unsigned short* __restrict__ w1p,
                                               float* __restrict__ h) {
    __shared__ __align__(16) unsigned short As[2][64 * BKq];  // 2 x 8 KB
    __shared__ __align__(16) unsigned short Bs[2][64 * BKq];  // 2 x 8 KB
    int m0 = blockIdx.x * 64;
    int j0 = blockIdx.y * 64;
    int kz = blockIdx.z;
    int tid = threadIdx.x;
    int r = tid >> 2, qq = tid & 3;
    const uint4* ap = (const uint4*)(pooled + (size_t)(m0 + r) * Fq + (size_t)kz * KCH) + qq;
    const uint4* bp = (const uint4*)(w1p + (size_t)(j0 + r) * Fq + (size_t)kz * KCH) + qq;
    int lane = tid & 63, wv = tid >> 6;
    int q = lane >> 4, mr = lane & 15;
    f32x4 acc0 = {0.f, 0.f, 0.f, 0.f};
    f32x4 acc1 = {0.f, 0.f, 0.f, 0.f};
    f32x4 acc2 = {0.f, 0.f, 0.f, 0.f};
    f32x4 acc3 = {0.f, 0.f, 0.f, 0.f};
    int st1 = r * 8 + ((qq) ^ (r & 7));
    int st2 = r * 8 + ((qq ^ 4) ^ (r & 7));
    int sA = (wv * 16 + mr) * 8;
    int c0k0 = (q) ^ (mr & 7);        // kk=0 chunk
    int c0k1 = (q ^ 4) ^ (mr & 7);    // kk=1 chunk

    uint4 a0v = ap[0], a1v = ap[4];
    uint4 b0v = bp[0], b1v = bp[4];
    {   // write step 0 into buf 0
        uint4* aw = (uint4*)As[0];
        uint4* bw = (uint4*)Bs[0];
        aw[st1] = a0v; aw[st2] = a1v;
        bw[st1] = b0v; bw[st2] = b1v;
    }
    a0v = ap[8];  a1v = ap[12];
    b0v = bp[8];  b1v = bp[12];
    for (int s = 0; s < KSTEPS; ++s) {
        __syncthreads();
        int cur = s & 1;
        if (s + 1 < KSTEPS) {
            uint4* aw = (uint4*)As[cur ^ 1];
            uint4* bw = (uint4*)Bs[cur ^ 1];
            aw[st1] = a0v; aw[st2] = a1v;
            bw[st1] = b0v; bw[st2] = b1v;
            if (s + 2 < KSTEPS) {
                a0v = ap[(s + 2) * 8];     a1v = ap[(s + 2) * 8 + 4];
                b0v = bp[(s + 2) * 8];     b1v = bp[(s + 2) * 8 + 4];
            }
        }
        const bf16x8* Ab = (const bf16x8*)As[cur];
        const bf16x8* Bb = (const bf16x8*)Bs[cur];
        bf16x8 a0 = Ab[sA + c0k0];
        bf16x8 a1 = Ab[sA + c0k1];
        acc0 = __builtin_amdgcn_mfma_f32_16x16x32_bf16(a0, Bb[(0  + mr) * 8 + c0k0], acc0, 0, 0, 0);
        acc1 = __builtin_amdgcn_mfma_f32_16x16x32_bf16(a0, Bb[(16 + mr) * 8 + c0k0], acc1, 0, 0, 0);
        acc2 = __builtin_amdgcn_mfma_f32_16x16x32_bf16(a0, Bb[(32 + mr) * 8 + c0k0], acc2, 0, 0, 0);
        acc3 = __builtin_amdgcn_mfma_f32_16x16x32_bf16(a0, Bb[(48 + mr) * 8 + c0k0], acc3, 0, 0, 0);
        acc0 = __builtin_amdgcn_mfma_f32_16x16x32_bf16(a1, Bb[(0  + mr) * 8 + c0k1], acc0, 0, 0, 0);
        acc1 = __builtin_amdgcn_mfma_f32_16x16x32_bf16(a1, Bb[(16 + mr) * 8 + c0k1], acc1, 0, 0, 0);
        acc2 = __builtin_amdgcn_mfma_f32_16x16x32_bf16(a1, Bb[(32 + mr) * 8 + c0k1], acc2, 0, 0, 0);
        acc3 = __builtin_amdgcn_mfma_f32_16x16x32_bf16(a1, Bb[(48 + mr) * 8 + c0k1], acc3, 0, 0, 0);
    }
    int mb = m0 + wv * 16 + q * 4;
    int jj = j0 + mr;
#pragma unroll
    for (int r2 = 0; r2 < 4; ++r2) {
        float* row = h + (size_t)(mb + r2) * HIDq + jj;
        atomicAdd(row + 0,  acc0[r2]);
        atomicAdd(row + 16, acc1[r2]);
        atomicAdd(row + 32, acc2[r2]);
        atomicAdd(row + 48, acc3[r2]);
    }
}

// K4: tail — ONE WAVE PER PROPOSAL (128 blocks x 4 waves). No LDS, no
// barrier. Lane owns 4 channels via float4 loads; 5 dots via FMA +
// 6-step shfl_xor butterfly; lane<5 writes epilogue.
__global__ __launch_bounds__(256) void k_tail(const float* __restrict__ h,
                                              const float* __restrict__ b1,
                                              const float* __restrict__ W2,
                                              const float* __restrict__ b2,
                                              const float* __restrict__ props,
                                              float* __restrict__ out) {
    int lane = threadIdx.x & 63, wv = threadIdx.x >> 6;
    int m = blockIdx.x * 4 + wv;
    int j4 = lane * 4;
    float4 hb = *(const float4*)(h + (size_t)m * HIDq + j4);
    float4 bb = *(const float4*)(b1 + j4);
    float hv0 = fmaxf(hb.x + bb.x, 0.f);
    float hv1 = fmaxf(hb.y + bb.y, 0.f);
    float hv2 = fmaxf(hb.z + bb.z, 0.f);
    float hv3 = fmaxf(hb.w + bb.w, 0.f);
    float s[OUTq];
#pragma unroll
    for (int o = 0; o < OUTq; ++o) {
        float4 w = *(const float4*)(W2 + (size_t)o * HIDq + j4);
        float v = hv0 * w.x + hv1 * w.y + hv2 * w.z + hv3 * w.w;
        v += __shfl_xor(v, 1);
        v += __shfl_xor(v, 2);
        v += __shfl_xor(v, 4);
        v += __shfl_xor(v, 8);
        v += __shfl_xor(v, 16);
        v += __shfl_xor(v, 32);
        s[o] = v;
    }
    if (lane < OUTq) {
        float so = lane == 0 ? s[0] : lane == 1 ? s[1] : lane == 2 ? s[2]
                 : lane == 3 ? s[3] : s[4];
        so += b2[lane];
        float pv = props[(size_t)m * 5 + lane];
        float r;
        if (lane < 4) r = pv + so;
        else r = 1.f / (1.f + expf(-(pv + so)));
        out[(size_t)m * 5 + lane] = r;
    }
}

extern "C" void kernel_launch(void* const* d_in, const int* in_sizes, int n_in,
                              void* d_out, int out_size, void* d_ws, size_t ws_size,
                              hipStream_t stream) {
    const float* feat  = (const float*)d_in[0];   // (4,256,23,30)
    const float* props = (const float*)d_in[1];   // (4,128,5)
    const float* W1    = (const float*)d_in[2];   // (256,12544)
    const float* b1    = (const float*)d_in[3];   // (256,)
    const float* W2    = (const float*)d_in[4];   // (5,256)
    const float* b2    = (const float*)d_in[5];   // (5,)
    float* out = (float*)d_out;

    char* ws = (char*)d_ws;
    unsigned short* ft     = (unsigned short*)(ws);              // 1,413,120 B (bf16)
    unsigned short* w1p    = (unsigned short*)(ws + 1413120);    // 6,422,528 B
    unsigned short* pooled = (unsigned short*)(ws + 7835648);    // 12,845,056 B
    float* h               = (float*)(ws + 20680704);            // 524,288 B -> 21,204,992 total

    k_prep<<<968, 256, 0, stream>>>(feat, ft, W1, w1p, h);
    k_pool<<<dim3(Mq, 13), 256, 0, stream>>>(ft, props, pooled);
    k_gemm1<<<dim3(8, 4, SPLITK), 256, 0, stream>>>(pooled, w1p, h);
    k_tail<<<Mq / 4, 256, 0, stream>>>(h, b1, W2, b2, props, out);
}

// Round 11
// 108.390 us; speedup vs baseline: 1.1635x; 1.0490x over previous
//
#include <hip/hip_runtime.h>
#include <math.h>

#define Bq 4
#define Nq 128
#define Cq 256
#define HFq 23
#define WFq 30
#define PHq 7
#define PWq 7
#define HIDq 256
#define OUTq 5
#define Fq (Cq*PHq*PWq)      // 12544
#define Mq (Bq*Nq)           // 512
#define HWq (HFq*WFq)        // 690
#define SCALEq (1.0f/32.0f)
#define NEGq (-1e30f)
#define KHq 5                // HF//PH + 2
#define KWq 6                // WF//PW + 2
#define SPLITK 14
#define KCH (Fq/SPLITK)      // 896
#define BKq 64
#define KSTEPS (KCH/BKq)     // 14

typedef float f32x4 __attribute__((ext_vector_type(4)));
typedef __bf16 bf16x8 __attribute__((ext_vector_type(8)));
typedef unsigned short u16x8 __attribute__((ext_vector_type(8)));

__device__ __forceinline__ unsigned short f2b(float f) {
    unsigned int u = __float_as_uint(f);
    unsigned int r = (u + 0x7FFFu + ((u >> 16) & 1u)) >> 16;
    return (unsigned short)r;
}

// K1: fused prep. blockIdx.x ranges:
//   [0,704)   : transpose features (B,C,HF,WF) f32 -> (B, HF*WF, C) bf16
//   [704,960) : W1 f32 (HID, c*49+cell) -> bf16 permuted (HID, cell*256+c)
//   [960,968) : zero h (atomicAdd target for split-K GEMM1)
__global__ __launch_bounds__(256) void k_prep(const float* __restrict__ feat,
                                              unsigned short* __restrict__ ft,
                                              const float* __restrict__ W1,
                                              unsigned short* __restrict__ w1p,
                                              float* __restrict__ h) {
    __shared__ __align__(16) unsigned short smem[Fq];   // 25088 B overlay
    int bid = blockIdx.x;
    int tid = threadIdx.x;
    if (bid < 704) {
        // --- transpose tile, f32 -> bf16 ---
        float (*t)[33] = (float (*)[33])smem;           // 32*33*4 = 4224 B
        int bb  = bid / 176;
        int rem = bid % 176;
        int x0 = (rem % 22) * 32;      // HW dim
        int c0 = (rem / 22) * 32;      // C dim
        int tx = tid & 31, ty = tid >> 5;
        const float* src = feat + (size_t)bb * Cq * HWq;
        unsigned short* dst = ft + (size_t)bb * HWq * Cq;
#pragma unroll
        for (int i = 0; i < 4; ++i) {
            int c = c0 + ty + i * 8;
            int x = x0 + tx;
            if (x < HWq) t[ty + i * 8][tx] = src[(size_t)c * HWq + x];  // t[c_loc][x_loc]
        }
        __syncthreads();
        int u = tid & 15, xl = tid >> 4;
#pragma unroll
        for (int i = 0; i < 2; ++i) {
            int xloc = xl + i * 16;
            int x = x0 + xloc;
            if (x < HWq) {
                ushort2 o;
                o.x = f2b(t[u * 2][xloc]);
                o.y = f2b(t[u * 2 + 1][xloc]);
                *(ushort2*)(dst + (size_t)x * Cq + c0 + u * 2) = o;
            }
        }
    } else if (bid < 960) {
        // --- W1 permute + bf16 convert ---
        int j = bid - 704;
        const float4* src = (const float4*)(W1 + (size_t)j * Fq);
        for (int i = tid; i < Fq / 4; i += 256) {
            float4 v = src[i];
            ushort4 o;
            o.x = f2b(v.x); o.y = f2b(v.y); o.z = f2b(v.z); o.w = f2b(v.w);
            ((ushort4*)smem)[i] = o;
        }
        __syncthreads();
        uint4* dst = (uint4*)(w1p + (size_t)j * Fq);
        for (int i = tid; i < Fq / 8; i += 256) {
            int base = i * 8;
            int cell = base >> 8;       // 8 consecutive c share one cell
            int c0v = base & 255;
            unsigned short tmp[8];
#pragma unroll
            for (int u2 = 0; u2 < 8; ++u2) tmp[u2] = smem[(c0v + u2) * 49 + cell];
            dst[i] = *(const uint4*)tmp;
        }
    } else {
        // --- zero h: 512 KB, 8 blocks x 256 threads x 16 float4 ---
        f32x4* h4 = (f32x4*)h;
        int base = (bid - 960) * 4096;
        f32x4 z = {0.f, 0.f, 0.f, 0.f};
#pragma unroll
        for (int u2 = 0; u2 < 16; ++u2) h4[base + u2 * 256 + tid] = z;
    }
}

// K2: ROI max pool over bf16 ft. ONE CELL PER WAVE: grid (Mq,13), wave g =
// blockIdx.y*4+wave handles cell g (g<49). ~25k waves -> max latency hiding.
__global__ __launch_bounds__(256) void k_pool(const unsigned short* __restrict__ ft,
                                              const float* __restrict__ props,
                                              unsigned short* __restrict__ pooled) {
    int wave = threadIdx.x >> 6;
    int lane = threadIdx.x & 63;
    int half = lane >> 5;
    int cl = lane & 31;
    int cell = blockIdx.y * 4 + wave;   // 0..51
    if (cell >= PHq * PWq) return;
    int m = blockIdx.x;              // proposal
    int b = m >> 7;
    const float* pr = props + (size_t)m * 5;
    float b0 = pr[0] * SCALEq, b1v = pr[1] * SCALEq;
    float b2v = pr[2] * SCALEq, b3v = pr[3] * SCALEq;
    int x1 = min(max((int)floorf(b0), 0), WFq - 1);
    int y1 = min(max((int)floorf(b1v), 0), HFq - 1);
    int rw = min(max((int)ceilf(b2v) - x1, 1), WFq);
    int rh = min(max((int)ceilf(b3v) - y1, 1), HFq);
    const unsigned short* ftb = ft + (size_t)b * HWq * Cq + cl * 8;
    unsigned short* pm = pooled + (size_t)m * Fq + cl * 8;

    int ph = cell / 7;
    int pw = cell - ph * 7;
    int hs = y1 + (ph * rh) / PHq;
    int he = min(y1 + ((ph + 1) * rh + PHq - 1) / PHq, HFq);
    int ws = x1 + (pw * rw) / PWq;
    int we = min(x1 + ((pw + 1) * rw + PWq - 1) / PWq, WFq);
    float acc[8];
#pragma unroll
    for (int u = 0; u < 8; ++u) acc[u] = NEGq;
#pragma unroll
    for (int kh = 0; kh < KHq; ++kh) {
        if (hs + kh < he) {                      // wave-uniform
            const unsigned short* rowp = ftb + (size_t)((hs + kh) * WFq) * Cq;
#pragma unroll
            for (int kw2 = 0; kw2 < 3; ++kw2) {
                int w = ws + kw2 * 2 + half;
                if (w < we) {                    // half-wave divergent only
                    u16x8 v = *(const u16x8*)(rowp + (size_t)w * Cq);
#pragma unroll
                    for (int u = 0; u < 8; ++u)
                        acc[u] = fmaxf(acc[u], __uint_as_float((unsigned)v[u] << 16));
                }
            }
        }
    }
#pragma unroll
    for (int u = 0; u < 8; ++u) acc[u] = fmaxf(acc[u], __shfl_xor(acc[u], 32));
    if (half == 0) {
        u16x8 o;
#pragma unroll
        for (int u = 0; u < 8; ++u) o[u] = f2b(acc[u]);
        *(u16x8*)(pm + (size_t)cell * Cq) = o;
    }
}

// K3: GEMM1 with MFMA bf16 — the verified R6 form, byte-identical.
// BM=64, BN=64, BK=64, SPLITK=14, double-buffered LDS with XOR-swizzled
// 16B chunks, 2-step register lookahead, atomicAdd split-K into h.
// LOCAL OPTIMUM — BM=128, SPLITK=28, and fused epilogues all regressed.
__global__ __launch_bounds__(256) void k_gemm1(const unsigned short* __restrict__ pooled,
                                               const unsigned short* __restrict__ w1p,
                                               float* __restrict__ h) {
    __shared__ __align__(16) unsigned short As[2][64 * BKq];  // 2 x 8 KB
    __shared__ __align__(16) unsigned short Bs[2][64 * BKq];  // 2 x 8 KB
    int m0 = blockIdx.x * 64;
    int j0 = blockIdx.y * 64;
    int kz = blockIdx.z;
    int tid = threadIdx.x;
    int r = tid >> 2, qq = tid & 3;
    const uint4* ap = (const uint4*)(pooled + (size_t)(m0 + r) * Fq + (size_t)kz * KCH) + qq;
    const uint4* bp = (const uint4*)(w1p + (size_t)(j0 + r) * Fq + (size_t)kz * KCH) + qq;
    int lane = tid & 63, wv = tid >> 6;
    int q = lane >> 4, mr = lane & 15;
    f32x4 acc0 = {0.f, 0.f, 0.f, 0.f};
    f32x4 acc1 = {0.f, 0.f, 0.f, 0.f};
    f32x4 acc2 = {0.f, 0.f, 0.f, 0.f};
    f32x4 acc3 = {0.f, 0.f, 0.f, 0.f};
    int st1 = r * 8 + ((qq) ^ (r & 7));
    int st2 = r * 8 + ((qq ^ 4) ^ (r & 7));
    int sA = (wv * 16 + mr) * 8;
    int c0k0 = (q) ^ (mr & 7);        // kk=0 chunk
    int c0k1 = (q ^ 4) ^ (mr & 7);    // kk=1 chunk

    uint4 a0v = ap[0], a1v = ap[4];
    uint4 b0v = bp[0], b1v = bp[4];
    {   // write step 0 into buf 0
        uint4* aw = (uint4*)As[0];
        uint4* bw = (uint4*)Bs[0];
        aw[st1] = a0v; aw[st2] = a1v;
        bw[st1] = b0v; bw[st2] = b1v;
    }
    a0v = ap[8];  a1v = ap[12];
    b0v = bp[8];  b1v = bp[12];
    for (int s = 0; s < KSTEPS; ++s) {
        __syncthreads();
        int cur = s & 1;
        if (s + 1 < KSTEPS) {
            uint4* aw = (uint4*)As[cur ^ 1];
            uint4* bw = (uint4*)Bs[cur ^ 1];
            aw[st1] = a0v; aw[st2] = a1v;
            bw[st1] = b0v; bw[st2] = b1v;
            if (s + 2 < KSTEPS) {
                a0v = ap[(s + 2) * 8];     a1v = ap[(s + 2) * 8 + 4];
                b0v = bp[(s + 2) * 8];     b1v = bp[(s + 2) * 8 + 4];
            }
        }
        const bf16x8* Ab = (const bf16x8*)As[cur];
        const bf16x8* Bb = (const bf16x8*)Bs[cur];
        bf16x8 a0 = Ab[sA + c0k0];
        bf16x8 a1 = Ab[sA + c0k1];
        acc0 = __builtin_amdgcn_mfma_f32_16x16x32_bf16(a0, Bb[(0  + mr) * 8 + c0k0], acc0, 0, 0, 0);
        acc1 = __builtin_amdgcn_mfma_f32_16x16x32_bf16(a0, Bb[(16 + mr) * 8 + c0k0], acc1, 0, 0, 0);
        acc2 = __builtin_amdgcn_mfma_f32_16x16x32_bf16(a0, Bb[(32 + mr) * 8 + c0k0], acc2, 0, 0, 0);
        acc3 = __builtin_amdgcn_mfma_f32_16x16x32_bf16(a0, Bb[(48 + mr) * 8 + c0k0], acc3, 0, 0, 0);
        acc0 = __builtin_amdgcn_mfma_f32_16x16x32_bf16(a1, Bb[(0  + mr) * 8 + c0k1], acc0, 0, 0, 0);
        acc1 = __builtin_amdgcn_mfma_f32_16x16x32_bf16(a1, Bb[(16 + mr) * 8 + c0k1], acc1, 0, 0, 0);
        acc2 = __builtin_amdgcn_mfma_f32_16x16x32_bf16(a1, Bb[(32 + mr) * 8 + c0k1], acc2, 0, 0, 0);
        acc3 = __builtin_amdgcn_mfma_f32_16x16x32_bf16(a1, Bb[(48 + mr) * 8 + c0k1], acc3, 0, 0, 0);
    }
    int mb = m0 + wv * 16 + q * 4;
    int jj = j0 + mr;
#pragma unroll
    for (int r2 = 0; r2 < 4; ++r2) {
        float* row = h + (size_t)(mb + r2) * HIDq + jj;
        atomicAdd(row + 0,  acc0[r2]);
        atomicAdd(row + 16, acc1[r2]);
        atomicAdd(row + 32, acc2[r2]);
        atomicAdd(row + 48, acc3[r2]);
    }
}

// K4: tail — ONE WAVE PER PROPOSAL (128 blocks x 4 waves). No LDS, no
// barrier. Lane owns 4 channels via float4 loads; 5 dots via FMA +
// 6-step shfl_xor butterfly; lane<5 writes epilogue.
__global__ __launch_bounds__(256) void k_tail(const float* __restrict__ h,
                                              const float* __restrict__ b1,
                                              const float* __restrict__ W2,
                                              const float* __restrict__ b2,
                                              const float* __restrict__ props,
                                              float* __restrict__ out) {
    int lane = threadIdx.x & 63, wv = threadIdx.x >> 6;
    int m = blockIdx.x * 4 + wv;
    int j4 = lane * 4;
    float4 hb = *(const float4*)(h + (size_t)m * HIDq + j4);
    float4 bb = *(const float4*)(b1 + j4);
    float hv0 = fmaxf(hb.x + bb.x, 0.f);
    float hv1 = fmaxf(hb.y + bb.y, 0.f);
    float hv2 = fmaxf(hb.z + bb.z, 0.f);
    float hv3 = fmaxf(hb.w + bb.w, 0.f);
    float s[OUTq];
#pragma unroll
    for (int o = 0; o < OUTq; ++o) {
        float4 w = *(const float4*)(W2 + (size_t)o * HIDq + j4);
        float v = hv0 * w.x + hv1 * w.y + hv2 * w.z + hv3 * w.w;
        v += __shfl_xor(v, 1);
        v += __shfl_xor(v, 2);
        v += __shfl_xor(v, 4);
        v += __shfl_xor(v, 8);
        v += __shfl_xor(v, 16);
        v += __shfl_xor(v, 32);
        s[o] = v;
    }
    if (lane < OUTq) {
        float so = lane == 0 ? s[0] : lane == 1 ? s[1] : lane == 2 ? s[2]
                 : lane == 3 ? s[3] : s[4];
        so += b2[lane];
        float pv = props[(size_t)m * 5 + lane];
        float r;
        if (lane < 4) r = pv + so;
        else r = 1.f / (1.f + expf(-(pv + so)));
        out[(size_t)m * 5 + lane] = r;
    }
}

extern "C" void kernel_launch(void* const* d_in, const int* in_sizes, int n_in,
                              void* d_out, int out_size, void* d_ws, size_t ws_size,
                              hipStream_t stream) {
    const float* feat  = (const float*)d_in[0];   // (4,256,23,30)
    const float* props = (const float*)d_in[1];   // (4,128,5)
    const float* W1    = (const float*)d_in[2];   // (256,12544)
    const float* b1    = (const float*)d_in[3];   // (256,)
    const float* W2    = (const float*)d_in[4];   // (5,256)
    const float* b2    = (const float*)d_in[5];   // (5,)
    float* out = (float*)d_out;

    char* ws = (char*)d_ws;
    unsigned short* ft     = (unsigned short*)(ws);              // 1,413,120 B (bf16)
    unsigned short* w1p    = (unsigned short*)(ws + 1413120);    // 6,422,528 B
    unsigned short* pooled = (unsigned short*)(ws + 7835648);    // 12,845,056 B
    float* h               = (float*)(ws + 20680704);            // 524,288 B -> 21,204,992 total

    k_prep<<<968, 256, 0, stream>>>(feat, ft, W1, w1p, h);
    k_pool<<<dim3(Mq, 13), 256, 0, stream>>>(ft, props, pooled);
    k_gemm1<<<dim3(8, 4, SPLITK), 256, 0, stream>>>(pooled, w1p, h);
    k_tail<<<Mq / 4, 256, 0, stream>>>(h, b1, W2, b2, props, out);
}